// Round 5
// baseline (238.403 us; speedup 1.0000x reference)
//
#include <hip/hip_runtime.h>

#define BATCH 4
#define SEQ   2048
#define EMB   128
#define NH    16
#define DK    8

#define SPLITS 4
#define KCHUNK (SEQ / SPLITS)   // 512 keys per split group

// log2(e) / sqrt(8): fold softmax temperature into exp2 (pre-multiplied into q)
#define QSCALE 0.510069726f

// ---------------------------------------------------------------------------
// Kernel 1: quantum features, coalesced via LDS tile.
// Block: 256 threads, one b, 32 consecutive s-rows. Stage 32x128 floats
// (16 KB) with lane-contiguous float4 loads, then 512 (s,h) cells (2/thread)
// compute the 8-element cumprod-cos from LDS and write f contiguously.
// f layout: f[(b*16+h)*2048 + s][8].
// ---------------------------------------------------------------------------
__global__ void feat_kernel(const float* __restrict__ x,
                            const float* __restrict__ theta,
                            float* __restrict__ f /* [64][2048][8] */) {
  __shared__ float Xs[32][132];   // 132 pitch: 16B-aligned rows, breaks pow2

  const int tid = threadIdx.x;
  const int b   = blockIdx.x >> 6;          // 4 b
  const int s0  = (blockIdx.x & 63) * 32;   // 64 s-tiles of 32

  // stage 32 rows x 128 cols, fully coalesced
#pragma unroll
  for (int it = 0; it < 4; ++it) {
    const int idx = it * 256 + tid;   // 1024 float4
    const int r  = idx >> 5;
    const int e4 = idx & 31;
    const float4 v = *(const float4*)(x + ((size_t)b * SEQ + s0 + r) * EMB + e4 * 4);
    *(float4*)&Xs[r][e4 * 4] = v;
  }

  float th[DK];
#pragma unroll
  for (int i = 0; i < DK; ++i) th[i] = theta[i];
  __syncthreads();

#pragma unroll
  for (int it = 0; it < 2; ++it) {
    const int id = it * 256 + tid;    // 512 cells
    const int s = id & 31;
    const int h = id >> 5;
    const float* xr = &Xs[s][h * 8];
    const float f0 = __cosf(xr[0] + th[0]);
    const float f1 = f0 * __cosf(xr[1] + th[1]);
    const float f2 = f1 * __cosf(xr[2] + th[2]);
    const float f3 = f2 * __cosf(xr[3] + th[3]);
    const float f4 = f3 * __cosf(xr[4] + th[4]);
    const float f5 = f4 * __cosf(xr[5] + th[5]);
    const float f6 = f5 * __cosf(xr[6] + th[6]);
    const float f7 = f6 * __cosf(xr[7] + th[7]);
    float4* fp = (float4*)(f + (((size_t)(b * NH + h)) * SEQ + s0 + s) * DK);
    fp[0] = make_float4(f0, f1, f2, f3);
    fp[1] = make_float4(f4, f5, f6, f7);
  }
}

// ---------------------------------------------------------------------------
// Kernel 2: self-attention (q == k == v), key-split x4 inside the block.
// Block = 1024 threads = 256 rows x 4 key-splits; grid = 512 -> 2 blocks/CU
// -> 32 waves/CU. Keys scalarized (readfirstlane-uniform split) -> s_load,
// VMEM pipe stays empty. unroll 8: deeper s_load prefetch (~64 SGPRs of keys
// in flight) to cover scalar-cache latency.
// exp2 via raw v_exp_f32: |d| <= 8/sqrt(8)*log2e ~ 4.1, exact there.
// ---------------------------------------------------------------------------
__launch_bounds__(1024, 8)
__global__ void attn_kernel(const float* __restrict__ f,
                            float* __restrict__ att /* [B*S][128] = d_out */) {
  __shared__ float part[SPLITS][256][9];   // 36 KB, 9-stride: conflict-free

  const int tid   = threadIdx.x;
  const int rloc  = tid & 255;
  // tid>>8 is constant across a 64-lane wave; make that visible -> SGPR
  const int split = __builtin_amdgcn_readfirstlane(tid >> 8);
  const int bh    = blockIdx.x >> 3;
  const int chunk = blockIdx.x & 7;
  const int row   = chunk * 256 + rloc;

  const float4* __restrict__ kf = (const float4*)(f + (size_t)bh * SEQ * DK);

  // own query row, pre-scaled
  const float4 qa = kf[2 * row];
  const float4 qb = kf[2 * row + 1];
  const float q0 = qa.x * QSCALE, q1 = qa.y * QSCALE;
  const float q2 = qa.z * QSCALE, q3 = qa.w * QSCALE;
  const float q4 = qb.x * QSCALE, q5 = qb.y * QSCALE;
  const float q6 = qb.z * QSCALE, q7 = qb.w * QSCALE;

  float a0 = 0.f, a1 = 0.f, a2 = 0.f, a3 = 0.f;
  float a4 = 0.f, a5 = 0.f, a6 = 0.f, a7 = 0.f;
  float den = 0.f;

  const int j0 = split * KCHUNK;
#pragma unroll 8
  for (int j = j0; j < j0 + KCHUNK; ++j) {
    const float4 ka = kf[2 * j];      // scalar (uniform) address -> s_load
    const float4 kb = kf[2 * j + 1];
    float d = q0 * ka.x;
    d = fmaf(q1, ka.y, d);
    d = fmaf(q2, ka.z, d);
    d = fmaf(q3, ka.w, d);
    d = fmaf(q4, kb.x, d);
    d = fmaf(q5, kb.y, d);
    d = fmaf(q6, kb.z, d);
    d = fmaf(q7, kb.w, d);
    const float w = __builtin_amdgcn_exp2f(d);  // raw v_exp_f32
    den += w;
    a0 = fmaf(w, ka.x, a0);
    a1 = fmaf(w, ka.y, a1);
    a2 = fmaf(w, ka.z, a2);
    a3 = fmaf(w, ka.w, a3);
    a4 = fmaf(w, kb.x, a4);
    a5 = fmaf(w, kb.y, a5);
    a6 = fmaf(w, kb.z, a6);
    a7 = fmaf(w, kb.w, a7);
  }

  // ---- combine the 4 key-split partials through LDS ----
  if (split != 0) {
    float* p = &part[split][rloc][0];
    p[0] = a0; p[1] = a1; p[2] = a2; p[3] = a3;
    p[4] = a4; p[5] = a5; p[6] = a6; p[7] = a7;
    p[8] = den;
  }
  __syncthreads();

  if (split == 0) {
#pragma unroll
    for (int s = 1; s < SPLITS; ++s) {
      const float* p = &part[s][rloc][0];
      a0 += p[0]; a1 += p[1]; a2 += p[2]; a3 += p[3];
      a4 += p[4]; a5 += p[5]; a6 += p[6]; a7 += p[7];
      den += p[8];
    }
    const int b = bh >> 4;
    const int h = bh & 15;
    const float inv = 1.0f / den;
    float* op = att + ((size_t)b * SEQ + row) * EMB + h * DK;
    ((float4*)op)[0] = make_float4(a0 * inv, a1 * inv, a2 * inv, a3 * inv);
    ((float4*)op)[1] = make_float4(a4 * inv, a5 * inv, a6 * inv, a7 * inv);
  }
}

// ---------------------------------------------------------------------------
// Kernel 3: output projection, IN-PLACE on d_out. out[r,c] = sum_e A[r,e]W[c,e]
// v3: A-tile (64x132 = 33 KB) in LDS row-major (float4 copy, no transpose);
// W read DIRECTLY from global per 4-e step (addresses shared across the 16
// ty-lanes -> broadcast; W is 64 KB, L1/L2-hot). Per 4e per wave: 8 ds_read
// _b128 (96 cyc) vs 128 FMA (256 cyc) -> VALU-bound. 4 rows x 8 cols/thread.
// In-place safe: block owns 64 rows x all cols; A fully staged before writes.
// ---------------------------------------------------------------------------
__launch_bounds__(256, 1)
__global__ void proj_kernel(float* __restrict__ AO /* A and out, in-place */,
                            const float* __restrict__ W) {
  __shared__ float As[64][132];   // 33 KB

  const int tid = threadIdx.x;
  const int tx = tid & 15;   // col group: cols tx*8 + jj
  const int ty = tid >> 4;   // row group: rows ty*4 + i
  const int rowbase = blockIdx.x * 64;

  // stage A tile: 64 rows x 128 -> 2048 float4, 8/thread, coalesced
#pragma unroll
  for (int it = 0; it < 8; ++it) {
    const int idx = it * 256 + tid;
    const int r  = idx >> 5;
    const int e4 = idx & 31;
    const float4 v = *(const float4*)(AO + (size_t)(rowbase + r) * EMB + e4 * 4);
    *(float4*)&As[r][e4 * 4] = v;
  }
  __syncthreads();

  float acc[4][8] = {{0.f}};

  for (int e = 0; e < EMB; e += 4) {
    float4 wv[8];
#pragma unroll
    for (int jj = 0; jj < 8; ++jj)
      wv[jj] = *(const float4*)(W + (size_t)(tx * 8 + jj) * EMB + e);
    float4 av[4];
#pragma unroll
    for (int i = 0; i < 4; ++i) av[i] = *(const float4*)&As[ty * 4 + i][e];
#pragma unroll
    for (int i = 0; i < 4; ++i)
#pragma unroll
      for (int jj = 0; jj < 8; ++jj) {
        acc[i][jj] = fmaf(av[i].x, wv[jj].x, acc[i][jj]);
        acc[i][jj] = fmaf(av[i].y, wv[jj].y, acc[i][jj]);
        acc[i][jj] = fmaf(av[i].z, wv[jj].z, acc[i][jj]);
        acc[i][jj] = fmaf(av[i].w, wv[jj].w, acc[i][jj]);
      }
  }

#pragma unroll
  for (int i = 0; i < 4; ++i) {
    float* op = AO + (size_t)(rowbase + ty * 4 + i) * EMB + tx * 8;
    ((float4*)op)[0] = make_float4(acc[i][0], acc[i][1], acc[i][2], acc[i][3]);
    ((float4*)op)[1] = make_float4(acc[i][4], acc[i][5], acc[i][6], acc[i][7]);
  }
}

// ---------------------------------------------------------------------------
extern "C" void kernel_launch(void* const* d_in, const int* in_sizes, int n_in,
                              void* d_out, int out_size, void* d_ws, size_t ws_size,
                              hipStream_t stream) {
  const float* x     = (const float*)d_in[0];  // [4,2048,128]
  const float* theta = (const float*)d_in[1];  // [8]
  const float* w_out = (const float*)d_in[2];  // [128,128]
  float* out = (float*)d_out;                  // [4,2048,128]; also att scratch
  float* f   = (float*)d_ws;                   // [64,2048,8] features (4 MB)

  // features: 4 b x 64 s-tiles = 256 blocks
  feat_kernel<<<dim3(256), dim3(256), 0, stream>>>(x, theta, f);

  // attention: 64 bh x 8 row-chunks = 512 blocks of 1024 (256 rows x 4 splits)
  attn_kernel<<<dim3(512), dim3(1024), 0, stream>>>(f, out);

  // projection in-place on d_out: 16384/64 = 256 blocks
  proj_kernel<<<dim3((BATCH * SEQ) / 64), dim3(256), 0, stream>>>(out, w_out);
}

// Round 6
// 110.757 us; speedup vs baseline: 2.1525x; 2.1525x over previous
//
#include <hip/hip_runtime.h>

#define BATCH 4
#define SEQ   2048
#define EMB   128
#define NH    16
#define DK    8

// log2(e) / sqrt(8): fold softmax temperature into exp2 (pre-multiplied into Qh)
#define QSCALE 0.510069726f

typedef _Float16 v4h __attribute__((ext_vector_type(4)));
typedef _Float16 v8h __attribute__((ext_vector_type(8)));
typedef float    v4f __attribute__((ext_vector_type(4)));

#define CHUNK 1024          // keys staged per LDS stage (2 stages cover SEQ)
#define VTP   1032          // VT row pitch (f16): breaks pow2 bank stride

// ---------------------------------------------------------------------------
// Kernel 1: quantum features -> f16. Fh[bh][s][8] = cumprod cos(x+theta),
// Qh = Fh * QSCALE (pre-scaled query copy). Coalesced via LDS x-tile.
// ---------------------------------------------------------------------------
__global__ void feat_kernel(const float* __restrict__ x,
                            const float* __restrict__ theta,
                            _Float16* __restrict__ Fh,
                            _Float16* __restrict__ Qh) {
  __shared__ float Xs[32][132];

  const int tid = threadIdx.x;
  const int b   = blockIdx.x >> 6;
  const int s0  = (blockIdx.x & 63) * 32;

#pragma unroll
  for (int it = 0; it < 4; ++it) {
    const int idx = it * 256 + tid;
    const int r  = idx >> 5;
    const int e4 = idx & 31;
    const float4 v = *(const float4*)(x + ((size_t)b * SEQ + s0 + r) * EMB + e4 * 4);
    *(float4*)&Xs[r][e4 * 4] = v;
  }

  float th[DK];
#pragma unroll
  for (int i = 0; i < DK; ++i) th[i] = theta[i];
  __syncthreads();

#pragma unroll
  for (int it = 0; it < 2; ++it) {
    const int id = it * 256 + tid;
    const int s = id & 31;
    const int h = id >> 5;
    const float* xr = &Xs[s][h * 8];
    const float f0 = __cosf(xr[0] + th[0]);
    const float f1 = f0 * __cosf(xr[1] + th[1]);
    const float f2 = f1 * __cosf(xr[2] + th[2]);
    const float f3 = f2 * __cosf(xr[3] + th[3]);
    const float f4 = f3 * __cosf(xr[4] + th[4]);
    const float f5 = f4 * __cosf(xr[5] + th[5]);
    const float f6 = f5 * __cosf(xr[6] + th[6]);
    const float f7 = f6 * __cosf(xr[7] + th[7]);
    const size_t off = (((size_t)(b * NH + h)) * SEQ + s0 + s) * DK;
    v8h fv = {(_Float16)f0, (_Float16)f1, (_Float16)f2, (_Float16)f3,
              (_Float16)f4, (_Float16)f5, (_Float16)f6, (_Float16)f7};
    v8h qv = {(_Float16)(f0 * QSCALE), (_Float16)(f1 * QSCALE),
              (_Float16)(f2 * QSCALE), (_Float16)(f3 * QSCALE),
              (_Float16)(f4 * QSCALE), (_Float16)(f5 * QSCALE),
              (_Float16)(f6 * QSCALE), (_Float16)(f7 * QSCALE)};
    *(v8h*)(Fh + off) = fv;
    *(v8h*)(Qh + off) = qv;
  }
}

// ---------------------------------------------------------------------------
// Kernel 2: MFMA attention. Block = 256 thr = 4 waves, one bh, 256 q-rows
// (wave owns 64 q = 4 16-row tiles). Grid = 64 bh x 8 = 512 blocks.
//
// Per 16-key tile:  S^T = mfma_16x16x16_f16(A=K, B=Q^T)   [key x q]
//   C-layout: lane{q=L&15, keys=quad*4+r}  ==  B-frag layout {n=L&15,
//   k=quad*4+j} needed by  out^T = mfma(A=V^T, B=P^T, acc). So
//   P = exp2(S^T) converts C->B IN REGISTERS (no LDS transpose).
// Ones-row d=8 in V^T accumulates the softmax denominator for free.
// K padded 8->16 with zeros (quads 2-3 zero frags).
// ---------------------------------------------------------------------------
__launch_bounds__(256, 2)
__global__ void attn_kernel(const _Float16* __restrict__ Fh,
                            const _Float16* __restrict__ Qh,
                            float* __restrict__ att /* d_out */) {
  __shared__ __align__(16) _Float16 Kl[CHUNK * 8];   // 16 KB: [key][8 dims]
  __shared__ __align__(16) _Float16 VT[16][VTP];     // 33 KB: [d][key], d=8 ones

  const int tid  = threadIdx.x;
  const int L    = tid & 63;
  const int wv   = tid >> 6;        // wave 0..3
  const int quad = L >> 4;
  const int ln   = L & 15;
  const int bh   = blockIdx.x >> 3;
  const int qb   = (blockIdx.x & 7) * 256 + wv * 64;

  const _Float16* __restrict__ fbase = Fh + (size_t)bh * SEQ * DK;
  const _Float16* __restrict__ qbase = Qh + (size_t)bh * SEQ * DK;

  // one-time init: VT row 8 = 1.0 (denominator), rows 9-15 = 0
  for (int i = tid; i < 8 * VTP / 4; i += 256) {
    v4h v = (i < VTP / 4) ? (v4h){(_Float16)1.f, (_Float16)1.f,
                                  (_Float16)1.f, (_Float16)1.f}
                          : (v4h){0, 0, 0, 0};
    *(v4h*)(&VT[8][0] + i * 4) = v;
  }

  // Q-frags: B-layout, lane{q=ln, dims quad*4+j}; quads 2-3 = zero pad
  v4h qf[4];
#pragma unroll
  for (int t = 0; t < 4; ++t) {
    v4h q = {0, 0, 0, 0};
    const int qrow = qb + t * 16 + ln;
    if (quad < 2) q = *(const v4h*)(qbase + (size_t)qrow * DK + quad * 4);
    qf[t] = q;
  }

  v4f acc[4];
#pragma unroll
  for (int t = 0; t < 4; ++t) acc[t] = (v4f){0.f, 0.f, 0.f, 0.f};
  const v4f zf = (v4f){0.f, 0.f, 0.f, 0.f};

  for (int c = 0; c < 2; ++c) {
    if (c) __syncthreads();       // protect restage vs previous compute
    const _Float16* fc = fbase + (size_t)c * CHUNK * DK;
    // stage Kl: 1024 keys x 16 B, coalesced float4 copies
#pragma unroll
    for (int it = 0; it < 4; ++it) {
      const int key = it * 256 + tid;
      *(float4*)&Kl[key * 8] = *(const float4*)(fc + key * 8);
    }
    // stage VT rows 0-7: thread owns 4 consecutive keys, packs per-dim v4h
    {
      const int k4 = tid * 4;
      const v8h r0 = *(const v8h*)(fc + (size_t)(k4 + 0) * 8);
      const v8h r1 = *(const v8h*)(fc + (size_t)(k4 + 1) * 8);
      const v8h r2 = *(const v8h*)(fc + (size_t)(k4 + 2) * 8);
      const v8h r3 = *(const v8h*)(fc + (size_t)(k4 + 3) * 8);
#pragma unroll
      for (int d = 0; d < 8; ++d) {
        v4h w = {r0[d], r1[d], r2[d], r3[d]};
        *(v4h*)&VT[d][k4] = w;
      }
    }
    __syncthreads();

    for (int t16 = 0; t16 < CHUNK / 16; ++t16) {
      // K-frag (A): lane{key=t16*16+ln, dims quad*4+j}, quads 2-3 zero
      const v4h kv = *(const v4h*)&Kl[(t16 * 16 + ln) * 8 + (quad & 1) * 4];
      const v4h kf = (quad < 2) ? kv : (v4h){0, 0, 0, 0};
      // V^T-frag (A of PV): lane{d=ln, keys t16*16+quad*4+j}
      const v4h vt = *(const v4h*)&VT[ln][t16 * 16 + quad * 4];
#pragma unroll
      for (int t = 0; t < 4; ++t) {
        const v4f s = __builtin_amdgcn_mfma_f32_16x16x16f16(kf, qf[t], zf, 0, 0, 0);
        v4h pb;
        pb[0] = (_Float16)__builtin_amdgcn_exp2f(s[0]);
        pb[1] = (_Float16)__builtin_amdgcn_exp2f(s[1]);
        pb[2] = (_Float16)__builtin_amdgcn_exp2f(s[2]);
        pb[3] = (_Float16)__builtin_amdgcn_exp2f(s[3]);
        acc[t] = __builtin_amdgcn_mfma_f32_16x16x16f16(vt, pb, acc[t], 0, 0, 0);
      }
    }
  }

  // epilogue: acc[t] = out^T[d=quad*4+r][q=ln]; den lives at d=8 (lane 32+ln, r=0)
  const int b = bh >> 4;
  const int h = bh & 15;
#pragma unroll
  for (int t = 0; t < 4; ++t) {
    const float den = __shfl(acc[t][0], 32 + ln, 64);
    const float inv = 1.0f / den;
    if (quad < 2) {
      const int qrow = qb + t * 16 + ln;
      float4 o = make_float4(acc[t][0] * inv, acc[t][1] * inv,
                             acc[t][2] * inv, acc[t][3] * inv);
      *(float4*)(att + ((size_t)b * SEQ + qrow) * EMB + h * DK + quad * 4) = o;
    }
  }
}

// ---------------------------------------------------------------------------
// Kernel 3: output projection, IN-PLACE on d_out. out[r,c]=sum_e A[r,e]W[c,e].
// Both tiles in LDS row-major, staged with pure float4 copies (no transpose,
// no per-lane global scatter). A-reads broadcast across tx (free); W-reads
// <=2-way bank aliased (free). In-place safe: block owns 64 rows x all cols.
// ---------------------------------------------------------------------------
__launch_bounds__(256, 1)
__global__ void proj_kernel(float* __restrict__ AO,
                            const float* __restrict__ W) {
  __shared__ float As[64][132];    // 33.8 KB
  __shared__ float Ws[128][132];   // 67.6 KB

  const int tid = threadIdx.x;
  const int tx = tid & 15;   // col group: cols tx + 16*jj
  const int ty = tid >> 4;   // row group: rows ty*4 + i
  const int rowbase = blockIdx.x * 64;

#pragma unroll
  for (int it = 0; it < 8; ++it) {
    const int idx = it * 256 + tid;
    const int r  = idx >> 5;
    const int e4 = idx & 31;
    *(float4*)&As[r][e4 * 4] =
        *(const float4*)(AO + (size_t)(rowbase + r) * EMB + e4 * 4);
  }
#pragma unroll
  for (int it = 0; it < 16; ++it) {
    const int idx = it * 256 + tid;
    const int n  = idx >> 5;
    const int e4 = idx & 31;
    *(float4*)&Ws[n][e4 * 4] = *(const float4*)(W + (size_t)n * EMB + e4 * 4);
  }
  __syncthreads();

  float acc[4][8] = {{0.f}};

#pragma unroll 2
  for (int e = 0; e < EMB; e += 4) {
    float4 av[4], wvv[8];
#pragma unroll
    for (int i = 0; i < 4; ++i) av[i] = *(const float4*)&As[ty * 4 + i][e];
#pragma unroll
    for (int jj = 0; jj < 8; ++jj) wvv[jj] = *(const float4*)&Ws[tx + 16 * jj][e];
#pragma unroll
    for (int i = 0; i < 4; ++i)
#pragma unroll
      for (int jj = 0; jj < 8; ++jj) {
        acc[i][jj] = fmaf(av[i].x, wvv[jj].x, acc[i][jj]);
        acc[i][jj] = fmaf(av[i].y, wvv[jj].y, acc[i][jj]);
        acc[i][jj] = fmaf(av[i].z, wvv[jj].z, acc[i][jj]);
        acc[i][jj] = fmaf(av[i].w, wvv[jj].w, acc[i][jj]);
      }
  }

#pragma unroll
  for (int i = 0; i < 4; ++i) {
    float* op = AO + (size_t)(rowbase + ty * 4 + i) * EMB;
#pragma unroll
    for (int jj = 0; jj < 8; ++jj) op[tx + 16 * jj] = acc[i][jj];
  }
}

// ---------------------------------------------------------------------------
extern "C" void kernel_launch(void* const* d_in, const int* in_sizes, int n_in,
                              void* d_out, int out_size, void* d_ws, size_t ws_size,
                              hipStream_t stream) {
  const float* x     = (const float*)d_in[0];  // [4,2048,128]
  const float* theta = (const float*)d_in[1];  // [8]
  const float* w_out = (const float*)d_in[2];  // [128,128]
  float* out = (float*)d_out;                  // [4,2048,128]; att scratch
  _Float16* Fh = (_Float16*)d_ws;                          // 2 MB
  _Float16* Qh = (_Float16*)((char*)d_ws + (size_t)BATCH * NH * SEQ * DK * 2);

  feat_kernel<<<dim3(256), dim3(256), 0, stream>>>(x, theta, Fh, Qh);
  attn_kernel<<<dim3(512), dim3(256), 0, stream>>>(Fh, Qh, out);
  proj_kernel<<<dim3((BATCH * SEQ) / 64), dim3(256), 0, stream>>>(out, w_out);
}

// Round 7
// 102.926 us; speedup vs baseline: 2.3162x; 1.0761x over previous
//
#include <hip/hip_runtime.h>

#define BATCH 4
#define SEQ   2048
#define EMB   128
#define NH    16
#define DK    8

// log2(e) / sqrt(8): fold softmax temperature into exp2 (pre-multiplied into Qh)
#define QSCALE 0.510069726f

typedef _Float16 v4h __attribute__((ext_vector_type(4)));
typedef _Float16 v8h __attribute__((ext_vector_type(8)));
typedef float    v4f __attribute__((ext_vector_type(4)));

#define CHUNK 1024          // keys staged per LDS stage (2 stages cover SEQ)
#define VTP   1032          // VT row pitch (f16): breaks pow2 bank stride

// ---------------------------------------------------------------------------
// Kernel 1: quantum features -> f16. Fh[bh][s][8] = cumprod cos(x+theta),
// Qh = Fh * QSCALE. Coalesced via LDS x-tile. Also folds the tiny W->f16
// conversion (64 elems/block) to avoid a separate launch.
// ---------------------------------------------------------------------------
__global__ void feat_kernel(const float* __restrict__ x,
                            const float* __restrict__ theta,
                            const float* __restrict__ W,
                            _Float16* __restrict__ Fh,
                            _Float16* __restrict__ Qh,
                            _Float16* __restrict__ Wh) {
  __shared__ float Xs[32][132];

  const int tid = threadIdx.x;
  const int b   = blockIdx.x >> 6;
  const int s0  = (blockIdx.x & 63) * 32;

#pragma unroll
  for (int it = 0; it < 4; ++it) {
    const int idx = it * 256 + tid;
    const int r  = idx >> 5;
    const int e4 = idx & 31;
    const float4 v = *(const float4*)(x + ((size_t)b * SEQ + s0 + r) * EMB + e4 * 4);
    *(float4*)&Xs[r][e4 * 4] = v;
  }

  // fold W (16384 floats) -> Wh f16: 64 per block, 4 per thread (tid<16)
  if (tid < 16) {
    const int i4 = blockIdx.x * 64 + tid * 4;
    const float4 w = *(const float4*)(W + i4);
    v4h wh = {(_Float16)w.x, (_Float16)w.y, (_Float16)w.z, (_Float16)w.w};
    *(v4h*)(Wh + i4) = wh;
  }

  float th[DK];
#pragma unroll
  for (int i = 0; i < DK; ++i) th[i] = theta[i];
  __syncthreads();

#pragma unroll
  for (int it = 0; it < 2; ++it) {
    const int id = it * 256 + tid;
    const int s = id & 31;
    const int h = id >> 5;
    const float* xr = &Xs[s][h * 8];
    const float f0 = __cosf(xr[0] + th[0]);
    const float f1 = f0 * __cosf(xr[1] + th[1]);
    const float f2 = f1 * __cosf(xr[2] + th[2]);
    const float f3 = f2 * __cosf(xr[3] + th[3]);
    const float f4 = f3 * __cosf(xr[4] + th[4]);
    const float f5 = f4 * __cosf(xr[5] + th[5]);
    const float f6 = f5 * __cosf(xr[6] + th[6]);
    const float f7 = f6 * __cosf(xr[7] + th[7]);
    const size_t off = (((size_t)(b * NH + h)) * SEQ + s0 + s) * DK;
    v8h fv = {(_Float16)f0, (_Float16)f1, (_Float16)f2, (_Float16)f3,
              (_Float16)f4, (_Float16)f5, (_Float16)f6, (_Float16)f7};
    v8h qv = {(_Float16)(f0 * QSCALE), (_Float16)(f1 * QSCALE),
              (_Float16)(f2 * QSCALE), (_Float16)(f3 * QSCALE),
              (_Float16)(f4 * QSCALE), (_Float16)(f5 * QSCALE),
              (_Float16)(f6 * QSCALE), (_Float16)(f7 * QSCALE)};
    *(v8h*)(Fh + off) = fv;
    *(v8h*)(Qh + off) = qv;
  }
}

// ---------------------------------------------------------------------------
// Kernel 2: MFMA attention (unchanged math from R6). Per 16-key tile:
// S^T = mfma(A=K, B=Q^T); C-layout == B-frag layout, so P=exp2(S^T) feeds
// out^T = mfma(A=V^T, B=P^T, acc) entirely in registers. Ones-row d=8 in V^T
// gives the denominator. NEW: writes f16 Ah to workspace (no in-place proj).
// ---------------------------------------------------------------------------
__launch_bounds__(256, 2)
__global__ void attn_kernel(const _Float16* __restrict__ Fh,
                            const _Float16* __restrict__ Qh,
                            _Float16* __restrict__ Ah /* [B*S][128] f16 */) {
  __shared__ __align__(16) _Float16 Kl[CHUNK * 8];   // 16 KB: [key][8 dims]
  __shared__ __align__(16) _Float16 VT[16][VTP];     // 33 KB: [d][key]

  const int tid  = threadIdx.x;
  const int L    = tid & 63;
  const int wv   = tid >> 6;
  const int quad = L >> 4;
  const int ln   = L & 15;
  const int bh   = blockIdx.x >> 3;
  const int qb   = (blockIdx.x & 7) * 256 + wv * 64;

  const _Float16* __restrict__ fbase = Fh + (size_t)bh * SEQ * DK;
  const _Float16* __restrict__ qbase = Qh + (size_t)bh * SEQ * DK;

  // one-time init: VT row 8 = 1.0 (denominator), rows 9-15 = 0
  for (int i = tid; i < 8 * VTP / 4; i += 256) {
    v4h v = (i < VTP / 4) ? (v4h){(_Float16)1.f, (_Float16)1.f,
                                  (_Float16)1.f, (_Float16)1.f}
                          : (v4h){0, 0, 0, 0};
    *(v4h*)(&VT[8][0] + i * 4) = v;
  }

  // Q-frags: B-layout, lane{q=ln, dims quad*4+j}; quads 2-3 = zero pad
  v4h qf[4];
#pragma unroll
  for (int t = 0; t < 4; ++t) {
    v4h q = {0, 0, 0, 0};
    const int qrow = qb + t * 16 + ln;
    if (quad < 2) q = *(const v4h*)(qbase + (size_t)qrow * DK + quad * 4);
    qf[t] = q;
  }

  v4f acc[4];
#pragma unroll
  for (int t = 0; t < 4; ++t) acc[t] = (v4f){0.f, 0.f, 0.f, 0.f};
  const v4f zf = (v4f){0.f, 0.f, 0.f, 0.f};

  for (int c = 0; c < 2; ++c) {
    if (c) __syncthreads();
    const _Float16* fc = fbase + (size_t)c * CHUNK * DK;
#pragma unroll
    for (int it = 0; it < 4; ++it) {
      const int key = it * 256 + tid;
      *(float4*)&Kl[key * 8] = *(const float4*)(fc + key * 8);
    }
    {
      const int k4 = tid * 4;
      const v8h r0 = *(const v8h*)(fc + (size_t)(k4 + 0) * 8);
      const v8h r1 = *(const v8h*)(fc + (size_t)(k4 + 1) * 8);
      const v8h r2 = *(const v8h*)(fc + (size_t)(k4 + 2) * 8);
      const v8h r3 = *(const v8h*)(fc + (size_t)(k4 + 3) * 8);
#pragma unroll
      for (int d = 0; d < 8; ++d) {
        v4h w = {r0[d], r1[d], r2[d], r3[d]};
        *(v4h*)&VT[d][k4] = w;
      }
    }
    __syncthreads();

    for (int t16 = 0; t16 < CHUNK / 16; ++t16) {
      const v4h kv = *(const v4h*)&Kl[(t16 * 16 + ln) * 8 + (quad & 1) * 4];
      const v4h kf = (quad < 2) ? kv : (v4h){0, 0, 0, 0};
      const v4h vt = *(const v4h*)&VT[ln][t16 * 16 + quad * 4];
#pragma unroll
      for (int t = 0; t < 4; ++t) {
        const v4f s = __builtin_amdgcn_mfma_f32_16x16x16f16(kf, qf[t], zf, 0, 0, 0);
        v4h pb;
        pb[0] = (_Float16)__builtin_amdgcn_exp2f(s[0]);
        pb[1] = (_Float16)__builtin_amdgcn_exp2f(s[1]);
        pb[2] = (_Float16)__builtin_amdgcn_exp2f(s[2]);
        pb[3] = (_Float16)__builtin_amdgcn_exp2f(s[3]);
        acc[t] = __builtin_amdgcn_mfma_f32_16x16x16f16(vt, pb, acc[t], 0, 0, 0);
      }
    }
  }

  // epilogue: acc[t] = out^T[d=quad*4+r][q=ln]; den at d=8 = lane 32+ln, r=0
  const int b = bh >> 4;
  const int h = bh & 15;
#pragma unroll
  for (int t = 0; t < 4; ++t) {
    const float den = __shfl(acc[t][0], 32 + ln, 64);
    const float inv = 1.0f / den;
    if (quad < 2) {
      const int qrow = qb + t * 16 + ln;
      v4h o = {(_Float16)(acc[t][0] * inv), (_Float16)(acc[t][1] * inv),
               (_Float16)(acc[t][2] * inv), (_Float16)(acc[t][3] * inv)};
      *(v4h*)(Ah + ((size_t)b * SEQ + qrow) * EMB + h * DK + quad * 4) = o;
    }
  }
}

// ---------------------------------------------------------------------------
// Kernel 3: MFMA projection. out = Ah · W^T, fp32 out.
// W row-major IS the B-fragment source: B[k][n] = W[n][k] -> lane reads
// Whs[n=ln][k=quad*4+j] (ds_read_b64). Block: 64 rows x 128 cols, 4 waves,
// wave owns a 16-row band x 8 col-tiles; K = 128 -> 8 k-steps, 64 mfma/wave.
// LDS pitch 136 f16 (=68 words): 2-way bank alias only (free).
// ---------------------------------------------------------------------------
__launch_bounds__(256, 1)
__global__ void proj_kernel(const _Float16* __restrict__ Ah,
                            const _Float16* __restrict__ Wh,
                            float* __restrict__ out) {
  __shared__ __align__(16) _Float16 Ahs[64][136];    // 17 KB
  __shared__ __align__(16) _Float16 Whs[128][136];   // 35 KB

  const int tid  = threadIdx.x;
  const int L    = tid & 63;
  const int wv   = tid >> 6;
  const int quad = L >> 4;
  const int ln   = L & 15;
  const int rowbase = blockIdx.x * 64;

  // stage Ah tile: 64 rows x 128 f16 = 1024 16B-chunks, 4/thread, coalesced
#pragma unroll
  for (int it = 0; it < 4; ++it) {
    const int idx = it * 256 + tid;
    const int r  = idx >> 4;          // 0..63
    const int c8 = idx & 15;          // 16 chunks of 8 f16
    *(uint4*)&Ahs[r][c8 * 8] =
        *(const uint4*)(Ah + (size_t)(rowbase + r) * EMB + c8 * 8);
  }
  // stage Wh: 128 rows x 128 f16 = 2048 chunks, 8/thread
#pragma unroll
  for (int it = 0; it < 8; ++it) {
    const int idx = it * 256 + tid;
    const int n  = idx >> 4;
    const int c8 = idx & 15;
    *(uint4*)&Whs[n][c8 * 8] = *(const uint4*)(Wh + (size_t)n * EMB + c8 * 8);
  }
  __syncthreads();

  v4f acc[8];
#pragma unroll
  for (int nt = 0; nt < 8; ++nt) acc[nt] = (v4f){0.f, 0.f, 0.f, 0.f};

#pragma unroll
  for (int k8 = 0; k8 < 8; ++k8) {
    // A-frag: lane{m=ln (in band), k=quad*4+j}
    const v4h af = *(const v4h*)&Ahs[wv * 16 + ln][k8 * 16 + quad * 4];
#pragma unroll
    for (int nt = 0; nt < 8; ++nt) {
      const v4h bf = *(const v4h*)&Whs[nt * 16 + ln][k8 * 16 + quad * 4];
      acc[nt] = __builtin_amdgcn_mfma_f32_16x16x16f16(af, bf, acc[nt], 0, 0, 0);
    }
  }

  // C layout: col = ln, rows = quad*4 + reg
#pragma unroll
  for (int nt = 0; nt < 8; ++nt) {
    const int col = nt * 16 + ln;
#pragma unroll
    for (int r = 0; r < 4; ++r) {
      out[(size_t)(rowbase + wv * 16 + quad * 4 + r) * EMB + col] = acc[nt][r];
    }
  }
}

// ---------------------------------------------------------------------------
extern "C" void kernel_launch(void* const* d_in, const int* in_sizes, int n_in,
                              void* d_out, int out_size, void* d_ws, size_t ws_size,
                              hipStream_t stream) {
  const float* x     = (const float*)d_in[0];  // [4,2048,128]
  const float* theta = (const float*)d_in[1];  // [8]
  const float* w_out = (const float*)d_in[2];  // [128,128]
  float* out = (float*)d_out;                  // [4,2048,128]

  const size_t FSZ = (size_t)BATCH * NH * SEQ * DK;   // 1 Mi elements
  _Float16* Fh = (_Float16*)d_ws;                     // 2 MB
  _Float16* Qh = Fh + FSZ;                            // 2 MB
  _Float16* Ah = Qh + FSZ;                            // [16384][128] = 4 MB
  _Float16* Wh = Ah + (size_t)BATCH * SEQ * EMB;      // 32 KB

  feat_kernel<<<dim3(256), dim3(256), 0, stream>>>(x, theta, w_out, Fh, Qh, Wh);
  attn_kernel<<<dim3(512), dim3(256), 0, stream>>>(Fh, Qh, Ah);
  proj_kernel<<<dim3((BATCH * SEQ) / 64), dim3(256), 0, stream>>>(Ah, Wh, out);
}

// Round 8
// 97.887 us; speedup vs baseline: 2.4355x; 1.0515x over previous
//
#include <hip/hip_runtime.h>

#define BATCH 4
#define SEQ   2048
#define EMB   128
#define NH    16
#define DK    8

// log2(e) / sqrt(8): fold softmax temperature into exp2 (pre-multiplied into qf)
#define QSCALE 0.510069726f

typedef _Float16 v2h __attribute__((ext_vector_type(2)));
typedef _Float16 v4h __attribute__((ext_vector_type(4)));
typedef float    v4f __attribute__((ext_vector_type(4)));

#define CHUNK 1024          // keys staged per LDS stage (2 stages cover SEQ)
#define VTP   1032          // VT row pitch (f16): breaks pow2 bank stride

// ---------------------------------------------------------------------------
// Fused features + MFMA attention.
// Block = 512 thr = 8 waves, one bh, 256 q-rows (wave owns 32 q = 2 tiles).
// Grid = 64 bh x 8 = 512 blocks -> 2 blocks/CU -> 16 waves/CU.
//
// Staging computes quantum features IN-KERNEL: thread owns 2 adjacent keys,
// reads 2x32B of x, does 16 cos + cumprod (trivial: ~200 cyc/wave), writes
// Kl (b128) + VT (v2h per dim, conflict-free). q == k == v and q-rows are a
// subset of this bh's keys, so qf is read back from Kl (scaled by QSCALE in
// f16). Chunk order starts with the q-containing chunk; plain-exp softmax
// (|score*log2e/sqrt8| <= 4.1, features <= 1) is order-independent -> exact.
//
// Per 16-key tile: S^T = mfma_16x16x16_f16(A=K, B=Q^T). C-layout {q=L&15,
// key=quad*4+r} == B-frag layout {n=L&15, k=quad*4+j}, so P = exp2(S^T)
// feeds out^T = mfma(A=V^T, B=P^T, acc) entirely in registers.
// Ones-row d=8 of V^T accumulates the softmax denominator for free.
// ---------------------------------------------------------------------------
__launch_bounds__(512, 4)
__global__ void attn_kernel(const float* __restrict__ x,
                            const float* __restrict__ theta,
                            _Float16* __restrict__ Ah /* [B*S][128] f16 */) {
  __shared__ __align__(16) _Float16 Kl[CHUNK * 8];   // 16 KB: [key][8 dims]
  __shared__ __align__(16) _Float16 VT[16][VTP];     // 33 KB: [d][key]

  const int tid  = threadIdx.x;
  const int L    = tid & 63;
  const int wv   = tid >> 6;        // wave 0..7
  const int quad = L >> 4;
  const int ln   = L & 15;
  const int bh     = blockIdx.x >> 3;
  const int qchunk = blockIdx.x & 7;
  const int qb     = qchunk * 256 + wv * 32;   // wave's first q row
  const int b = bh >> 4;
  const int h = bh & 15;

  float th[DK];
#pragma unroll
  for (int i = 0; i < DK; ++i) th[i] = theta[i];

  // one-time init: VT row 8 = 1.0 (denominator), rows 9-15 = 0
  for (int i = tid; i < 8 * VTP / 4; i += 512) {
    v4h v = (i < VTP / 4) ? (v4h){(_Float16)1.f, (_Float16)1.f,
                                  (_Float16)1.f, (_Float16)1.f}
                          : (v4h){0, 0, 0, 0};
    *(v4h*)(&VT[8][0] + i * 4) = v;
  }

  const int c0 = qchunk >> 2;       // chunk containing this block's q rows
  v4h qf[2];
  v4f acc[2];
  acc[0] = (v4f){0.f, 0.f, 0.f, 0.f};
  acc[1] = (v4f){0.f, 0.f, 0.f, 0.f};
  const v4f zf = (v4f){0.f, 0.f, 0.f, 0.f};

  for (int cc = 0; cc < 2; ++cc) {
    const int c = cc ? (1 - c0) : c0;
    if (cc) __syncthreads();        // all waves done with previous chunk

    // ---- stage chunk c: compute features for 2 adjacent keys/thread ----
    {
      const int k2 = tid * 2;                    // local key 0..1022
      const float* xp = x + ((size_t)b * SEQ + c * CHUNK + k2) * EMB + h * DK;
      const float4 a0 = *(const float4*)(xp);
      const float4 a1 = *(const float4*)(xp + 4);
      const float4 b0 = *(const float4*)(xp + EMB);
      const float4 b1 = *(const float4*)(xp + EMB + 4);

      float r0[8], r1[8];
      r0[0] = __cosf(a0.x + th[0]);
      r0[1] = r0[0] * __cosf(a0.y + th[1]);
      r0[2] = r0[1] * __cosf(a0.z + th[2]);
      r0[3] = r0[2] * __cosf(a0.w + th[3]);
      r0[4] = r0[3] * __cosf(a1.x + th[4]);
      r0[5] = r0[4] * __cosf(a1.y + th[5]);
      r0[6] = r0[5] * __cosf(a1.z + th[6]);
      r0[7] = r0[6] * __cosf(a1.w + th[7]);
      r1[0] = __cosf(b0.x + th[0]);
      r1[1] = r1[0] * __cosf(b0.y + th[1]);
      r1[2] = r1[1] * __cosf(b0.z + th[2]);
      r1[3] = r1[2] * __cosf(b0.w + th[3]);
      r1[4] = r1[3] * __cosf(b1.x + th[4]);
      r1[5] = r1[4] * __cosf(b1.y + th[5]);
      r1[6] = r1[5] * __cosf(b1.z + th[6]);
      r1[7] = r1[6] * __cosf(b1.w + th[7]);

      _Float16 h0[8], h1[8];
#pragma unroll
      for (int i = 0; i < 8; ++i) { h0[i] = (_Float16)r0[i]; h1[i] = (_Float16)r1[i]; }

      // Kl: two contiguous 16B stores (keys k2, k2+1)
      union { v4h v[2]; float4 f; } u0, u1;
      u0.v[0] = (v4h){h0[0], h0[1], h0[2], h0[3]};
      u0.v[1] = (v4h){h0[4], h0[5], h0[6], h0[7]};
      u1.v[0] = (v4h){h1[0], h1[1], h1[2], h1[3]};
      u1.v[1] = (v4h){h1[4], h1[5], h1[6], h1[7]};
      *(float4*)&Kl[k2 * 8]     = u0.f;
      *(float4*)&Kl[k2 * 8 + 8] = u1.f;

      // VT: per-dim v2h (keys k2, k2+1) -> ds_write_b32, lane-consecutive
#pragma unroll
      for (int d = 0; d < 8; ++d) {
        v2h w = {h0[d], h1[d]};
        *(v2h*)&VT[d][k2] = w;
      }
    }
    __syncthreads();

    // qf from Kl on the first (q-containing) chunk
    if (cc == 0) {
      const v4h qsc = {(_Float16)QSCALE, (_Float16)QSCALE,
                       (_Float16)QSCALE, (_Float16)QSCALE};
#pragma unroll
      for (int t = 0; t < 2; ++t) {
        const int lrow = qb - c0 * CHUNK + t * 16 + ln;
        v4h q = {0, 0, 0, 0};
        if (quad < 2) q = *(const v4h*)&Kl[lrow * 8 + quad * 4];
        qf[t] = q * qsc;
      }
    }

    // ---- compute: 64 16-key tiles ----
    for (int t16 = 0; t16 < CHUNK / 16; ++t16) {
      const v4h kv = *(const v4h*)&Kl[(t16 * 16 + ln) * 8 + (quad & 1) * 4];
      const v4h kf = (quad < 2) ? kv : (v4h){0, 0, 0, 0};
      const v4h vt = *(const v4h*)&VT[ln][t16 * 16 + quad * 4];
#pragma unroll
      for (int t = 0; t < 2; ++t) {
        const v4f s = __builtin_amdgcn_mfma_f32_16x16x16f16(kf, qf[t], zf, 0, 0, 0);
        v4h pb;
        pb[0] = (_Float16)__builtin_amdgcn_exp2f(s[0]);
        pb[1] = (_Float16)__builtin_amdgcn_exp2f(s[1]);
        pb[2] = (_Float16)__builtin_amdgcn_exp2f(s[2]);
        pb[3] = (_Float16)__builtin_amdgcn_exp2f(s[3]);
        acc[t] = __builtin_amdgcn_mfma_f32_16x16x16f16(vt, pb, acc[t], 0, 0, 0);
      }
    }
  }

  // epilogue: acc[t] = out^T[d=quad*4+r][q=ln]; den at d=8 = lane 32+ln, r=0
#pragma unroll
  for (int t = 0; t < 2; ++t) {
    const float den = __shfl(acc[t][0], 32 + ln, 64);
    const float inv = 1.0f / den;
    if (quad < 2) {
      const int qrow = qb + t * 16 + ln;
      v4h o = {(_Float16)(acc[t][0] * inv), (_Float16)(acc[t][1] * inv),
               (_Float16)(acc[t][2] * inv), (_Float16)(acc[t][3] * inv)};
      *(v4h*)(Ah + ((size_t)b * SEQ + qrow) * EMB + h * DK + quad * 4) = o;
    }
  }
}

// ---------------------------------------------------------------------------
// MFMA projection. out = Ah · W^T, fp32 out. W converted f32->f16 during
// LDS staging (no separate buffer/kernel). W row-major IS the B-fragment
// source: B[k][n] = W[n][k] -> lane reads Whs[n=ln][k=quad*4+j].
// Block: 64 rows x 128 cols, 4 waves, wave owns a 16-row band x 8 col-tiles;
// K = 128 -> 8 k-steps, 64 mfma/wave. Pitch 136 f16 = 68 words: 2-way alias
// only (free).
// ---------------------------------------------------------------------------
__launch_bounds__(256, 1)
__global__ void proj_kernel(const _Float16* __restrict__ Ah,
                            const float* __restrict__ W,
                            float* __restrict__ out) {
  __shared__ __align__(16) _Float16 Ahs[64][136];    // 17 KB
  __shared__ __align__(16) _Float16 Whs[128][136];   // 35 KB

  const int tid  = threadIdx.x;
  const int L    = tid & 63;
  const int wv   = tid >> 6;
  const int quad = L >> 4;
  const int ln   = L & 15;
  const int rowbase = blockIdx.x * 64;

  // stage Ah tile: 64 rows x 128 f16 = 1024 16B-chunks, 4/thread, coalesced
#pragma unroll
  for (int it = 0; it < 4; ++it) {
    const int idx = it * 256 + tid;
    const int r  = idx >> 4;
    const int c8 = idx & 15;
    *(uint4*)&Ahs[r][c8 * 8] =
        *(const uint4*)(Ah + (size_t)(rowbase + r) * EMB + c8 * 8);
  }
  // stage W with inline f32->f16: 128 rows x 32 float4 = 4096, 16/thread
#pragma unroll
  for (int it = 0; it < 16; ++it) {
    const int idx = it * 256 + tid;
    const int n  = idx >> 5;
    const int c4 = idx & 31;
    const float4 w = *(const float4*)(W + (size_t)n * EMB + c4 * 4);
    v4h wh = {(_Float16)w.x, (_Float16)w.y, (_Float16)w.z, (_Float16)w.w};
    *(v4h*)&Whs[n][c4 * 4] = wh;
  }
  __syncthreads();

  v4f acc[8];
#pragma unroll
  for (int nt = 0; nt < 8; ++nt) acc[nt] = (v4f){0.f, 0.f, 0.f, 0.f};

#pragma unroll
  for (int k8 = 0; k8 < 8; ++k8) {
    const v4h af = *(const v4h*)&Ahs[wv * 16 + ln][k8 * 16 + quad * 4];
#pragma unroll
    for (int nt = 0; nt < 8; ++nt) {
      const v4h bf = *(const v4h*)&Whs[nt * 16 + ln][k8 * 16 + quad * 4];
      acc[nt] = __builtin_amdgcn_mfma_f32_16x16x16f16(af, bf, acc[nt], 0, 0, 0);
    }
  }

  // C layout: col = ln, rows = quad*4 + reg
#pragma unroll
  for (int nt = 0; nt < 8; ++nt) {
    const int col = nt * 16 + ln;
#pragma unroll
    for (int r = 0; r < 4; ++r) {
      out[(size_t)(rowbase + wv * 16 + quad * 4 + r) * EMB + col] = acc[nt][r];
    }
  }
}

// ---------------------------------------------------------------------------
extern "C" void kernel_launch(void* const* d_in, const int* in_sizes, int n_in,
                              void* d_out, int out_size, void* d_ws, size_t ws_size,
                              hipStream_t stream) {
  const float* x     = (const float*)d_in[0];  // [4,2048,128]
  const float* theta = (const float*)d_in[1];  // [8]
  const float* w_out = (const float*)d_in[2];  // [128,128]
  float* out = (float*)d_out;                  // [4,2048,128]

  _Float16* Ah = (_Float16*)d_ws;              // [16384][128] f16 = 4 MB

  // fused features + attention: 64 bh x 8 q-chunks, 512 thr (8 waves)
  attn_kernel<<<dim3(512), dim3(512), 0, stream>>>(x, theta, Ah);

  // projection: 16384/64 = 256 blocks
  proj_kernel<<<dim3((BATCH * SEQ) / 64), dim3(256), 0, stream>>>(Ah, w_out, out);
}

// Round 10
// 95.921 us; speedup vs baseline: 2.4854x; 1.0205x over previous
//
#include <hip/hip_runtime.h>

#define BATCH 4
#define SEQ   2048
#define EMB   128
#define NH    16
#define DK    8

// log2(e) / sqrt(8): fold softmax temperature into exp2 (pre-multiplied into qf)
#define QSCALE 0.510069726f

typedef _Float16 v2h __attribute__((ext_vector_type(2)));
typedef _Float16 v4h __attribute__((ext_vector_type(4)));
typedef __fp16   v2fp __attribute__((ext_vector_type(2)));
typedef float    v4f __attribute__((ext_vector_type(4)));

#define CHUNK  512          // keys per LDS stage (4 stages cover SEQ)
#define NCHUNK (SEQ / CHUNK)
#define VTP    520          // VT row pitch (f16): 260 words, breaks pow2 stride

// ---------------------------------------------------------------------------
// Fused features + MFMA attention.
// Block = 512 thr = 8 waves, one bh, 128 q-rows (wave owns 16 q = 1 tile).
// Grid = 64 bh x 16 = 1024 blocks; LDS ~25 KB -> 4 blocks/CU = 32 waves/CU
// = 8 waves/SIMD (full chip thread capacity).
//
// Staging computes quantum features IN-KERNEL: thread owns 1 key of the
// chunk, reads 32 B of x, 8 cos + cumprod, writes Kl (b128) + VT (8 x b16,
// lane-consecutive -> 2-way alias, free). q-rows are a subset of the keys,
// so qf is read back from Kl on the q-containing chunk (order-independent:
// plain-exp softmax, |score*log2e/sqrt8| <= 4.1 since features <= 1).
//
// Per 16-key tile: S^T = mfma_16x16x16_f16(A=K, B=Q^T). C-layout {q=L&15,
// key=quad*4+r} == B-frag layout {n=L&15, k=quad*4+j}, so P = exp2(S^T)
// feeds out^T = mfma(A=V^T, B=P^T, acc) entirely in registers; pack via
// v_cvt_pkrtz. Ones-row d=8 of V^T accumulates the denominator for free.
// ---------------------------------------------------------------------------
__launch_bounds__(512, 8)
__global__ void attn_kernel(const float* __restrict__ x,
                            const float* __restrict__ theta,
                            _Float16* __restrict__ Ah /* [B*S][128] f16 */) {
  __shared__ __align__(16) _Float16 Kl[CHUNK * 8];   // 8 KB: [key][8 dims]
  __shared__ __align__(16) _Float16 VT[16][VTP];     // 16.25 KB: [d][key]

  const int tid  = threadIdx.x;
  const int L    = tid & 63;
  const int quad = L >> 4;
  const int ln   = L & 15;
  const int wv   = tid >> 6;        // wave 0..7
  const int bh     = blockIdx.x >> 4;
  const int qchunk = blockIdx.x & 15;
  const int qb     = qchunk * 128 + wv * 16;   // wave's 16 q rows
  const int b = bh >> 4;
  const int h = bh & 15;

  float th[DK];
#pragma unroll
  for (int i = 0; i < DK; ++i) th[i] = theta[i];

  // one-time init: VT row 8 = 1.0 (denominator), rows 9-15 = 0
  for (int i = tid; i < 8 * VTP / 4; i += 512) {
    v4h v = (i < VTP / 4) ? (v4h){(_Float16)1.f, (_Float16)1.f,
                                  (_Float16)1.f, (_Float16)1.f}
                          : (v4h){0, 0, 0, 0};
    *(v4h*)(&VT[8][0] + i * 4) = v;
  }

  const int c0 = qchunk >> 2;       // chunk containing this block's q rows
  v4h qf = {0, 0, 0, 0};
  v4f acc = (v4f){0.f, 0.f, 0.f, 0.f};
  const v4f zf = (v4f){0.f, 0.f, 0.f, 0.f};

  for (int cc = 0; cc < NCHUNK; ++cc) {
    const int c = (c0 + cc) & (NCHUNK - 1);
    if (cc) __syncthreads();        // all waves done with previous chunk

    // ---- stage chunk c: thread computes features for key `tid` ----
    {
      const float* xp = x + ((size_t)b * SEQ + c * CHUNK + tid) * EMB + h * DK;
      const float4 a0 = *(const float4*)(xp);
      const float4 a1 = *(const float4*)(xp + 4);

      float r[8];
      r[0] = __cosf(a0.x + th[0]);
      r[1] = r[0] * __cosf(a0.y + th[1]);
      r[2] = r[1] * __cosf(a0.z + th[2]);
      r[3] = r[2] * __cosf(a0.w + th[3]);
      r[4] = r[3] * __cosf(a1.x + th[4]);
      r[5] = r[4] * __cosf(a1.y + th[5]);
      r[6] = r[5] * __cosf(a1.z + th[6]);
      r[7] = r[6] * __cosf(a1.w + th[7]);

      _Float16 hv[8];
#pragma unroll
      for (int i = 0; i < 8; ++i) hv[i] = (_Float16)r[i];

      union { v4h v[2]; float4 f; } u;
      u.v[0] = (v4h){hv[0], hv[1], hv[2], hv[3]};
      u.v[1] = (v4h){hv[4], hv[5], hv[6], hv[7]};
      *(float4*)&Kl[tid * 8] = u.f;

#pragma unroll
      for (int d = 0; d < 8; ++d) VT[d][tid] = hv[d];
    }
    __syncthreads();

    // qf from Kl on the q-containing chunk (cc == 0 visits c0 first)
    if (cc == 0) {
      const v4h qsc = {(_Float16)QSCALE, (_Float16)QSCALE,
                       (_Float16)QSCALE, (_Float16)QSCALE};
      const int lrow = qb - c0 * CHUNK + ln;
      if (quad < 2) qf = *(const v4h*)&Kl[lrow * 8 + quad * 4] * qsc;
    }

    // ---- compute: 32 16-key tiles ----
    for (int t16 = 0; t16 < CHUNK / 16; ++t16) {
      const v4h kv = *(const v4h*)&Kl[(t16 * 16 + ln) * 8 + (quad & 1) * 4];
      const v4h kf = (quad < 2) ? kv : (v4h){0, 0, 0, 0};
      const v4h vt = *(const v4h*)&VT[ln][t16 * 16 + quad * 4];
      const v4f s = __builtin_amdgcn_mfma_f32_16x16x16f16(kf, qf, zf, 0, 0, 0);
      union { v2fp p[2]; v4h v; } pk;
      pk.p[0] = __builtin_amdgcn_cvt_pkrtz(__builtin_amdgcn_exp2f(s[0]),
                                           __builtin_amdgcn_exp2f(s[1]));
      pk.p[1] = __builtin_amdgcn_cvt_pkrtz(__builtin_amdgcn_exp2f(s[2]),
                                           __builtin_amdgcn_exp2f(s[3]));
      acc = __builtin_amdgcn_mfma_f32_16x16x16f16(vt, pk.v, acc, 0, 0, 0);
    }
  }

  // epilogue: acc = out^T[d=quad*4+r][q=ln]; den at d=8 = lane 32+ln, r=0
  {
    const float den = __shfl(acc[0], 32 + ln, 64);
    const float inv = 1.0f / den;
    if (quad < 2) {
      const int qrow = qb + ln;
      v4h o = {(_Float16)(acc[0] * inv), (_Float16)(acc[1] * inv),
               (_Float16)(acc[2] * inv), (_Float16)(acc[3] * inv)};
      *(v4h*)(Ah + ((size_t)b * SEQ + qrow) * EMB + h * DK + quad * 4) = o;
    }
  }
}

// ---------------------------------------------------------------------------
// MFMA projection. out = Ah · W^T, fp32 out. W converted f32->f16 during LDS
// staging. W row-major IS the B-fragment source: B[k][n] = W[n][k] -> lane
// reads Whs[n=ln][k=quad*4+j]. Block: 64 rows x 64 cols (grid 256x2) ->
// LDS 35 KB -> 2 blocks/CU, 8 waves/CU. Wave: 16-row band x 4 col-tiles,
// K=128 -> 8 k-steps, 32 mfma/wave. Pitch 136 f16: 2-way alias only (free).
// ---------------------------------------------------------------------------
__launch_bounds__(256, 4)
__global__ void proj_kernel(const _Float16* __restrict__ Ah,
                            const float* __restrict__ W,
                            float* __restrict__ out) {
  __shared__ __align__(16) _Float16 Ahs[64][136];    // 17.4 KB
  __shared__ __align__(16) _Float16 Whs[64][136];    // 17.4 KB

  const int tid  = threadIdx.x;
  const int L    = tid & 63;
  const int wv   = tid >> 6;
  const int quad = L >> 4;
  const int ln   = L & 15;
  const int rowbase = blockIdx.x * 64;
  const int colbase = blockIdx.y * 64;

  // stage Ah tile: 64 rows x 128 f16 = 1024 16B-chunks, 4/thread, coalesced
#pragma unroll
  for (int it = 0; it < 4; ++it) {
    const int idx = it * 256 + tid;
    const int r  = idx >> 4;
    const int c8 = idx & 15;
    *(uint4*)&Ahs[r][c8 * 8] =
        *(const uint4*)(Ah + (size_t)(rowbase + r) * EMB + c8 * 8);
  }
  // stage W cols [colbase, +64) with inline f32->f16: 64 rows x 32 float4
#pragma unroll
  for (int it = 0; it < 8; ++it) {
    const int idx = it * 256 + tid;
    const int n  = idx >> 5;
    const int c4 = idx & 31;
    const float4 w = *(const float4*)(W + (size_t)(colbase + n) * EMB + c4 * 4);
    v4h wh = {(_Float16)w.x, (_Float16)w.y, (_Float16)w.z, (_Float16)w.w};
    *(v4h*)&Whs[n][c4 * 4] = wh;
  }
  __syncthreads();

  v4f acc[4];
#pragma unroll
  for (int nt = 0; nt < 4; ++nt) acc[nt] = (v4f){0.f, 0.f, 0.f, 0.f};

#pragma unroll
  for (int k8 = 0; k8 < 8; ++k8) {
    const v4h af = *(const v4h*)&Ahs[wv * 16 + ln][k8 * 16 + quad * 4];
#pragma unroll
    for (int nt = 0; nt < 4; ++nt) {
      const v4h bf = *(const v4h*)&Whs[nt * 16 + ln][k8 * 16 + quad * 4];
      acc[nt] = __builtin_amdgcn_mfma_f32_16x16x16f16(af, bf, acc[nt], 0, 0, 0);
    }
  }

  // C layout: col = ln, rows = quad*4 + reg
#pragma unroll
  for (int nt = 0; nt < 4; ++nt) {
    const int col = colbase + nt * 16 + ln;
#pragma unroll
    for (int r = 0; r < 4; ++r) {
      out[(size_t)(rowbase + wv * 16 + quad * 4 + r) * EMB + col] = acc[nt][r];
    }
  }
}

// ---------------------------------------------------------------------------
extern "C" void kernel_launch(void* const* d_in, const int* in_sizes, int n_in,
                              void* d_out, int out_size, void* d_ws, size_t ws_size,
                              hipStream_t stream) {
  const float* x     = (const float*)d_in[0];  // [4,2048,128]
  const float* theta = (const float*)d_in[1];  // [8]
  const float* w_out = (const float*)d_in[2];  // [128,128]
  float* out = (float*)d_out;                  // [4,2048,128]

  _Float16* Ah = (_Float16*)d_ws;              // [16384][128] f16 = 4 MB

  // fused features + attention: 64 bh x 16 q-chunks = 1024 blocks, 8 waves
  attn_kernel<<<dim3(1024), dim3(512), 0, stream>>>(x, theta, Ah);

  // projection: 256 row-tiles x 2 col-tiles
  proj_kernel<<<dim3((BATCH * SEQ) / 64, 2), dim3(256), 0, stream>>>(Ah, w_out, out);
}

// Round 11
// 94.163 us; speedup vs baseline: 2.5318x; 1.0187x over previous
//
#include <hip/hip_runtime.h>

#define BATCH 4
#define SEQ   2048
#define EMB   128
#define NH    16
#define DK    8

// log2(e) / sqrt(8): fold softmax temperature into exp2 (pre-multiplied into qf)
#define QSCALE 0.510069726f

typedef _Float16 v2h __attribute__((ext_vector_type(2)));
typedef _Float16 v4h __attribute__((ext_vector_type(4)));
typedef __fp16   v2fp __attribute__((ext_vector_type(2)));
typedef float    v4f __attribute__((ext_vector_type(4)));

#define CHUNK  512          // keys per LDS stage (4 stages cover SEQ)
#define NCHUNK (SEQ / CHUNK)
#define VTP    520          // VT row pitch (f16): 260 words, breaks pow2 stride

// ---------------------------------------------------------------------------
// Fused features + MFMA attention.
// Block = 256 thr = 4 waves; wave owns 32 q-rows (t=2 16-row tiles); block
// covers 128 q-rows. Grid = 64 bh x 16 = 1024 blocks; LDS 24.6 KB ->
// 6 blocks/CU = 24 waves/CU, with 2 independent exp->mfma chains per wave.
//
// Staging computes quantum features IN-KERNEL: thread owns 2 adjacent keys,
// 16 cos + cumprod, writes Kl (2x b128) + VT (8x packed v2h, conflict-free).
// q-rows are a subset of the keys, so qf is read back from Kl on the
// q-containing chunk (plain-exp softmax is order-independent:
// |score*log2e/sqrt8| <= 4.1 since features <= 1).
//
// Per 16-key tile: S^T = mfma_16x16x16_f16(A=K, B=Q^T). C-layout {q=L&15,
// key=quad*4+r} == B-frag layout {n=L&15, k=quad*4+j}, so P = exp2(S^T)
// feeds out^T = mfma(A=V^T, B=P^T, acc) entirely in registers (pkrtz pack).
// NOTE: no zero-select on the K fragment — qf is 0 in quads 2-3 (k>=8), so
// the padded-K garbage multiplies by zero. Ones-row d=8 of V^T gives the
// softmax denominator for free.
// ---------------------------------------------------------------------------
__launch_bounds__(256, 6)
__global__ void attn_kernel(const float* __restrict__ x,
                            const float* __restrict__ theta,
                            _Float16* __restrict__ Ah /* [B*S][128] f16 */) {
  __shared__ __align__(16) _Float16 Kl[CHUNK * 8];   // 8 KB: [key][8 dims]
  __shared__ __align__(16) _Float16 VT[16][VTP];     // 16.6 KB: [d][key]

  const int tid  = threadIdx.x;
  const int L    = tid & 63;
  const int quad = L >> 4;
  const int ln   = L & 15;
  const int wv   = tid >> 6;        // wave 0..3
  const int bh     = blockIdx.x >> 4;
  const int qchunk = blockIdx.x & 15;
  const int qb     = qchunk * 128 + wv * 32;   // wave's 32 q rows
  const int b = bh >> 4;
  const int h = bh & 15;

  float th[DK];
#pragma unroll
  for (int i = 0; i < DK; ++i) th[i] = theta[i];

  // one-time init: VT row 8 = 1.0 (denominator), rows 9-15 = 0
  for (int i = tid; i < 8 * VTP / 4; i += 256) {
    v4h v = (i < VTP / 4) ? (v4h){(_Float16)1.f, (_Float16)1.f,
                                  (_Float16)1.f, (_Float16)1.f}
                          : (v4h){0, 0, 0, 0};
    *(v4h*)(&VT[8][0] + i * 4) = v;
  }

  const int c0 = qchunk >> 2;       // chunk containing this block's q rows
  v4h qf[2] = {{0, 0, 0, 0}, {0, 0, 0, 0}};
  v4f acc[2];
  acc[0] = (v4f){0.f, 0.f, 0.f, 0.f};
  acc[1] = (v4f){0.f, 0.f, 0.f, 0.f};
  const v4f zf = (v4f){0.f, 0.f, 0.f, 0.f};

  for (int cc = 0; cc < NCHUNK; ++cc) {
    const int c = (c0 + cc) & (NCHUNK - 1);
    if (cc) __syncthreads();        // all waves done with previous chunk

    // ---- stage chunk c: thread computes features for keys 2*tid, 2*tid+1 ----
    {
      const int k2 = tid * 2;
      const float* xp = x + ((size_t)b * SEQ + c * CHUNK + k2) * EMB + h * DK;
      const float4 a0 = *(const float4*)(xp);
      const float4 a1 = *(const float4*)(xp + 4);
      const float4 b0 = *(const float4*)(xp + EMB);
      const float4 b1 = *(const float4*)(xp + EMB + 4);

      float r0[8], r1[8];
      r0[0] = __cosf(a0.x + th[0]);
      r0[1] = r0[0] * __cosf(a0.y + th[1]);
      r0[2] = r0[1] * __cosf(a0.z + th[2]);
      r0[3] = r0[2] * __cosf(a0.w + th[3]);
      r0[4] = r0[3] * __cosf(a1.x + th[4]);
      r0[5] = r0[4] * __cosf(a1.y + th[5]);
      r0[6] = r0[5] * __cosf(a1.z + th[6]);
      r0[7] = r0[6] * __cosf(a1.w + th[7]);
      r1[0] = __cosf(b0.x + th[0]);
      r1[1] = r1[0] * __cosf(b0.y + th[1]);
      r1[2] = r1[1] * __cosf(b0.z + th[2]);
      r1[3] = r1[2] * __cosf(b0.w + th[3]);
      r1[4] = r1[3] * __cosf(b1.x + th[4]);
      r1[5] = r1[4] * __cosf(b1.y + th[5]);
      r1[6] = r1[5] * __cosf(b1.z + th[6]);
      r1[7] = r1[6] * __cosf(b1.w + th[7]);

      _Float16 h0[8], h1[8];
#pragma unroll
      for (int i = 0; i < 8; ++i) { h0[i] = (_Float16)r0[i]; h1[i] = (_Float16)r1[i]; }

      union { v4h v[2]; float4 f; } u0, u1;
      u0.v[0] = (v4h){h0[0], h0[1], h0[2], h0[3]};
      u0.v[1] = (v4h){h0[4], h0[5], h0[6], h0[7]};
      u1.v[0] = (v4h){h1[0], h1[1], h1[2], h1[3]};
      u1.v[1] = (v4h){h1[4], h1[5], h1[6], h1[7]};
      *(float4*)&Kl[k2 * 8]     = u0.f;
      *(float4*)&Kl[k2 * 8 + 8] = u1.f;

#pragma unroll
      for (int d = 0; d < 8; ++d) {
        v2h w = {h0[d], h1[d]};
        *(v2h*)&VT[d][k2] = w;     // ds_write_b32, lane-consecutive
      }
    }
    __syncthreads();

    // qf from Kl on the q-containing chunk (cc == 0 visits c0 first)
    if (cc == 0) {
      const v4h qsc = {(_Float16)QSCALE, (_Float16)QSCALE,
                       (_Float16)QSCALE, (_Float16)QSCALE};
      const int lbase = qb - c0 * CHUNK + ln;
      if (quad < 2) {
        qf[0] = *(const v4h*)&Kl[(lbase)      * 8 + quad * 4] * qsc;
        qf[1] = *(const v4h*)&Kl[(lbase + 16) * 8 + quad * 4] * qsc;
      }
    }

    // ---- compute: 32 16-key tiles, 2 q-tiles each ----
#pragma unroll 4
    for (int t16 = 0; t16 < CHUNK / 16; ++t16) {
      const v4h kf = *(const v4h*)&Kl[(t16 * 16 + ln) * 8 + (quad & 1) * 4];
      const v4h vt = *(const v4h*)&VT[ln][t16 * 16 + quad * 4];
#pragma unroll
      for (int t = 0; t < 2; ++t) {
        const v4f s = __builtin_amdgcn_mfma_f32_16x16x16f16(kf, qf[t], zf, 0, 0, 0);
        union { v2fp p[2]; v4h v; } pk;
        pk.p[0] = __builtin_amdgcn_cvt_pkrtz(__builtin_amdgcn_exp2f(s[0]),
                                             __builtin_amdgcn_exp2f(s[1]));
        pk.p[1] = __builtin_amdgcn_cvt_pkrtz(__builtin_amdgcn_exp2f(s[2]),
                                             __builtin_amdgcn_exp2f(s[3]));
        acc[t] = __builtin_amdgcn_mfma_f32_16x16x16f16(vt, pk.v, acc[t], 0, 0, 0);
      }
    }
  }

  // epilogue: acc[t] = out^T[d=quad*4+r][q=ln]; den at d=8 = lane 32+ln, r=0
#pragma unroll
  for (int t = 0; t < 2; ++t) {
    const float den = __shfl(acc[t][0], 32 + ln, 64);
    const float inv = 1.0f / den;
    if (quad < 2) {
      const int qrow = qb + t * 16 + ln;
      v4h o = {(_Float16)(acc[t][0] * inv), (_Float16)(acc[t][1] * inv),
               (_Float16)(acc[t][2] * inv), (_Float16)(acc[t][3] * inv)};
      *(v4h*)(Ah + ((size_t)b * SEQ + qrow) * EMB + h * DK + quad * 4) = o;
    }
  }
}

// ---------------------------------------------------------------------------
// MFMA projection (unchanged from R10). out = Ah · W^T, fp32 out. W converted
// f32->f16 during LDS staging. W row-major IS the B-fragment source:
// B[k][n] = W[n][k] -> lane reads Whs[n=ln][k=quad*4+j]. Block: 64 rows x
// 64 cols (grid 256x2) -> LDS 35 KB, 4 blocks/CU, 16 waves/CU.
// ---------------------------------------------------------------------------
__launch_bounds__(256, 4)
__global__ void proj_kernel(const _Float16* __restrict__ Ah,
                            const float* __restrict__ W,
                            float* __restrict__ out) {
  __shared__ __align__(16) _Float16 Ahs[64][136];    // 17.4 KB
  __shared__ __align__(16) _Float16 Whs[64][136];    // 17.4 KB

  const int tid  = threadIdx.x;
  const int L    = tid & 63;
  const int wv   = tid >> 6;
  const int quad = L >> 4;
  const int ln   = L & 15;
  const int rowbase = blockIdx.x * 64;
  const int colbase = blockIdx.y * 64;

#pragma unroll
  for (int it = 0; it < 4; ++it) {
    const int idx = it * 256 + tid;
    const int r  = idx >> 4;
    const int c8 = idx & 15;
    *(uint4*)&Ahs[r][c8 * 8] =
        *(const uint4*)(Ah + (size_t)(rowbase + r) * EMB + c8 * 8);
  }
#pragma unroll
  for (int it = 0; it < 8; ++it) {
    const int idx = it * 256 + tid;
    const int n  = idx >> 5;
    const int c4 = idx & 31;
    const float4 w = *(const float4*)(W + (size_t)(colbase + n) * EMB + c4 * 4);
    v4h wh = {(_Float16)w.x, (_Float16)w.y, (_Float16)w.z, (_Float16)w.w};
    *(v4h*)&Whs[n][c4 * 4] = wh;
  }
  __syncthreads();

  v4f acc[4];
#pragma unroll
  for (int nt = 0; nt < 4; ++nt) acc[nt] = (v4f){0.f, 0.f, 0.f, 0.f};

#pragma unroll
  for (int k8 = 0; k8 < 8; ++k8) {
    const v4h af = *(const v4h*)&Ahs[wv * 16 + ln][k8 * 16 + quad * 4];
#pragma unroll
    for (int nt = 0; nt < 4; ++nt) {
      const v4h bf = *(const v4h*)&Whs[nt * 16 + ln][k8 * 16 + quad * 4];
      acc[nt] = __builtin_amdgcn_mfma_f32_16x16x16f16(af, bf, acc[nt], 0, 0, 0);
    }
  }

#pragma unroll
  for (int nt = 0; nt < 4; ++nt) {
    const int col = colbase + nt * 16 + ln;
#pragma unroll
    for (int r = 0; r < 4; ++r) {
      out[(size_t)(rowbase + wv * 16 + quad * 4 + r) * EMB + col] = acc[nt][r];
    }
  }
}

// ---------------------------------------------------------------------------
extern "C" void kernel_launch(void* const* d_in, const int* in_sizes, int n_in,
                              void* d_out, int out_size, void* d_ws, size_t ws_size,
                              hipStream_t stream) {
  const float* x     = (const float*)d_in[0];  // [4,2048,128]
  const float* theta = (const float*)d_in[1];  // [8]
  const float* w_out = (const float*)d_in[2];  // [128,128]
  float* out = (float*)d_out;                  // [4,2048,128]

  _Float16* Ah = (_Float16*)d_ws;              // [16384][128] f16 = 4 MB

  // fused features + attention: 64 bh x 16 q-chunks = 1024 blocks, 4 waves
  attn_kernel<<<dim3(1024), dim3(256), 0, stream>>>(x, theta, Ah);

  // projection: 256 row-tiles x 2 col-tiles
  proj_kernel<<<dim3((BATCH * SEQ) / 64, 2), dim3(256), 0, stream>>>(Ah, w_out, out);
}